// Round 5
// baseline (225.985 us; speedup 1.0000x reference)
//
#include <hip/hip_runtime.h>

// Encoding layer. B=16, C=512, N=4096, K=32.
// v6: fix per-wave MLP in GEMM1. Evidence: reduce_kernel streams at 5.3 TB/s
// with 1 wave/SIMD (32 independent loads/thread in flight), while every
// enc variant delivers ~2.1 TB/s with all pipes idle -> the MFMA-coupled
// load->convert->consume chain serializes ~700cy round trips. Changes vs v5:
//  - GEMM1 x-loads go through two explicit 16-float register buffers:
//    consume one (f2bf + xs + 2 MFMA) while the other's 16 loads fly,
//    refill right after consumption. ~16-32 outstanding loads/wave.
//  - __launch_bounds__(256,2): grid already limits to 2 blocks/CU; the
//    (256,3) VGPR cap (84) was only strangling the pipeline.
//  - Everything else unchanged from v5 (2 lgkm-only barriers, GEMM2 ring,
//    f32-cw epilogue, 32 MiB partials + reduce).

#define B_ 16
#define C_ 512
#define N_ 4096
#define K_ 32
#define CHUNK 128                 // tokens per block
#define NCH (N_ / CHUNK)          // 32 chunks per batch
#define NBLK (B_ * NCH)           // 512 blocks
#define WLS 40                    // Wl n-stride (u16): 80 B

typedef __attribute__((ext_vector_type(8))) short short8;
typedef __attribute__((ext_vector_type(16))) float floatx16;

__device__ inline unsigned short f2bf(float f) {
    union { float f; unsigned u; } v; v.f = f;
    unsigned r = v.u + 0x7FFFu + ((v.u >> 16) & 1u);  // RNE
    return (unsigned short)(r >> 16);
}

// LDS-drain-only barrier: keeps global loads (vmcnt) in flight across it.
__device__ inline void cbar() {
    __builtin_amdgcn_sched_barrier(0);
    asm volatile("s_waitcnt lgkmcnt(0)" ::: "memory");
    __builtin_amdgcn_s_barrier();
    __builtin_amdgcn_sched_barrier(0);
}

template <int USE_WS>
__global__ __launch_bounds__(256, 2)
void enc_kernel(const float* __restrict__ x,
                const float* __restrict__ cw,
                const float* __restrict__ scale,
                float* __restrict__ outp)
{
    __shared__ unsigned short Wl[4][K_ * WLS];   // softmax w bf16 [tile][k][n], 10240 B
    __shared__ float csq[K_];
    __shared__ float scl[K_];

    const int tid  = threadIdx.x;
    const int wave = tid >> 6;
    const int lane = tid & 63;
    const int l31  = lane & 31;
    const int lh   = lane >> 5;

    const int b     = blockIdx.x >> 5;           // NCH = 32
    const int chunk = blockIdx.x & (NCH - 1);
    const float* xb = x + (long)b * C_ * N_;

    // ========== GEMM1 load plumbing (issue first, before csq VALU work) ======
    // wave owns tokens n = chunk*128 + wave*32 + l31; contraction over c in 16
    // half-groups of 32 c-rows. Element (ss,j) of half hh: c = hh*32+ss*16+lh*8+j.
    const float* xcol = xb + chunk * CHUNK + wave * 32 + l31;

    float xva[16], xvb[16];
#define XLOADH(buf_, hh_)                                                      \
    { const float* xg_ = xcol + (long)((hh_) * 32 + lh * 8) * N_;              \
      _Pragma("unroll")                                                        \
      for (int ss = 0; ss < 2; ++ss)                                           \
          _Pragma("unroll")                                                    \
          for (int j = 0; j < 8; ++j)                                          \
              buf_[ss * 8 + j] = xg_[(long)(ss * 16 + j) * N_]; }

    XLOADH(xva, 0)      // half 0 in flight
    XLOADH(xvb, 1)      // half 1 in flight

    // ---- prologue: scale + csq (VALU work overlaps the x loads) ----
    if (tid < K_) scl[tid] = scale[tid];
    {
        const int k = tid >> 3, q = tid & 7;      // k row, 64-c slice
        const float4* src = (const float4*)(cw + k * C_ + q * 64);
        float ssum = 0.f;
        #pragma unroll
        for (int i = 0; i < 16; ++i) {
            const float4 v = src[i];
            ssum += v.x*v.x + v.y*v.y + v.z*v.z + v.w*v.w;
        }
        ssum += __shfl_xor(ssum, 1);
        ssum += __shfl_xor(ssum, 2);
        ssum += __shfl_xor(ssum, 4);
        if (q == 0) csq[k] = ssum;
    }

    // GEMM1 A-fragments: f32 cw rows (L2-hot) converted in-register.
    const float* cwr = cw + l31 * C_ + lh * 8;
    short8 afA[4], afB[4];
#define AFLOADG(buf_, ptr_)                                                    \
    { _Pragma("unroll")                                                        \
      for (int s = 0; s < 4; ++s) {                                            \
          const float4 u0 = *(const float4*)((ptr_) + s * 16);                 \
          const float4 u1 = *(const float4*)((ptr_) + s * 16 + 4);             \
          short8 t_;                                                           \
          t_[0] = (short)f2bf(u0.x); t_[1] = (short)f2bf(u0.y);                \
          t_[2] = (short)f2bf(u0.z); t_[3] = (short)f2bf(u0.w);                \
          t_[4] = (short)f2bf(u1.x); t_[5] = (short)f2bf(u1.y);                \
          t_[6] = (short)f2bf(u1.z); t_[7] = (short)f2bf(u1.w);                \
          buf_[s] = t_; } }

    floatx16 S;
    #pragma unroll
    for (int i = 0; i < 16; ++i) S[i] = 0.f;
    float xs = 0.f;

    // consume half (g = hh>>1 selects afA/afB; h = hh&1 selects frag pair)
#define XCONS(buf_, g_, h_)                                                    \
    { _Pragma("unroll")                                                        \
      for (int ss = 0; ss < 2; ++ss) {                                         \
          short8 bx;                                                           \
          _Pragma("unroll")                                                    \
          for (int j = 0; j < 8; ++j) {                                        \
              const float xv_ = buf_[ss * 8 + j];                              \
              xs += xv_ * xv_;                                                 \
              bx[j] = (short)f2bf(xv_);                                        \
          }                                                                    \
          S = __builtin_amdgcn_mfma_f32_32x32x16_bf16(                         \
                  ((g_) & 1) ? afB[(h_) * 2 + ss] : afA[(h_) * 2 + ss],        \
                  bx, S, 0, 0, 0);                                             \
      } }

    AFLOADG(afA, cwr)   // g=0 fragments

    // ====== GEMM1 main: 16 halves, 2-deep register pipeline ======
    #pragma unroll
    for (int hh = 0; hh < 16; ++hh) {
        const int g = hh >> 1, h = hh & 1;
        if (h == 0 && g + 1 < 8) {     // prefetch next group's A-frags
            if (g & 1) AFLOADG(afA, cwr + (g + 1) * 64)
            else       AFLOADG(afB, cwr + (g + 1) * 64)
        }
        if (hh & 1) {
            XCONS(xvb, g, h)
            if (hh + 2 < 16) XLOADH(xvb, hh + 2)
        } else {
            XCONS(xva, g, h)
            if (hh + 2 < 16) XLOADH(xva, hh + 2)
        }
    }

    // lane pair (lh=0, lh=1) covered complementary halves of c for token l31
    xs += __shfl_xor(xs, 32);

    // ---- GEMM2 ring prefetch (independent of softmax; flies through it) ----
    float4 bv[6][2];
#define G2LOAD(bi_, i_)                                                        \
    { const int t_ = (i_) >> 3, st_ = (i_) & 7;                                \
      const int c_ = wave * 128 + t_ * 32 + l31;                               \
      const int no_ = (st_ >> 1) * 32 + (st_ & 1) * 16 + lh * 8;               \
      const float* p_ = xb + (long)c_ * N_ + chunk * CHUNK + no_;              \
      bv[bi_][0] = *(const float4*)p_;                                         \
      bv[bi_][1] = *(const float4*)(p_ + 4); }
    G2LOAD(0, 0)
    G2LOAD(1, 1)
    G2LOAD(2, 2)
    G2LOAD(3, 3)
    G2LOAD(4, 4)
    G2LOAD(5, 5)

    cbar();      // csq/scl visible (lgkm-only: ring stays in flight)

    // ---- softmax over k: lane pair (l31, l31+32) holds 16 k's each ----
    {
        const float xq = xs;
        float L[16], mx = -3.4e38f;
        #pragma unroll
        for (int rr = 0; rr < 16; ++rr) {
            const int k = (rr & 3) + 8 * (rr >> 2) + 4 * lh;
            L[rr] = scl[k] * (xq - 2.f * S[rr] + csq[k]);
            mx = fmaxf(mx, L[rr]);
        }
        mx = fmaxf(mx, __shfl_xor(mx, 32));
        float sum = 0.f;
        #pragma unroll
        for (int rr = 0; rr < 16; ++rr) { L[rr] = __expf(L[rr] - mx); sum += L[rr]; }
        sum += __shfl_xor(sum, 32);
        const float inv = 1.f / sum;
        #pragma unroll
        for (int rr = 0; rr < 16; ++rr) {
            const int k = (rr & 3) + 8 * (rr >> 2) + 4 * lh;
            Wl[wave][k * WLS + l31] = f2bf(L[rr] * inv);
        }
    }
    cbar();      // Wl handoff

    // ========== GEMM2: enc[k][c] = sum_n W[k][n] x[n][c] ==========
    short8 aw[8];
    #pragma unroll
    for (int st = 0; st < 8; ++st)
        aw[st] = *(const short8*)&Wl[st >> 1][l31 * WLS + (st & 1) * 16 + lh * 8];

    floatx16 wacc;
    #pragma unroll
    for (int i = 0; i < 16; ++i) wacc[i] = 0.f;
    {
        short8 ones;
        #pragma unroll
        for (int j = 0; j < 8; ++j) ones[j] = (short)0x3F80;
        #pragma unroll
        for (int st = 0; st < 8; ++st)
            wacc = __builtin_amdgcn_mfma_f32_32x32x16_bf16(aw[st], ones, wacc, 0, 0, 0);
    }

    floatx16 acc[4];
    #pragma unroll
    for (int t = 0; t < 4; ++t)
        #pragma unroll
        for (int i = 0; i < 16; ++i) acc[t][i] = 0.f;

    #pragma unroll
    for (int i = 0; i < 32; ++i) {               // i = t*8 + st
        const int bi = i % 6;
        const int t  = i >> 3, st = i & 7;
        const float4 v0 = bv[bi][0];
        const float4 v1 = bv[bi][1];
        short8 bx;
        bx[0] = (short)f2bf(v0.x); bx[1] = (short)f2bf(v0.y);
        bx[2] = (short)f2bf(v0.z); bx[3] = (short)f2bf(v0.w);
        bx[4] = (short)f2bf(v1.x); bx[5] = (short)f2bf(v1.y);
        bx[6] = (short)f2bf(v1.z); bx[7] = (short)f2bf(v1.w);
        acc[t] = __builtin_amdgcn_mfma_f32_32x32x16_bf16(aw[st], bx, acc[t], 0, 0, 0);
        if (i + 6 < 32) G2LOAD(bi, i + 6)
    }

    // ---- epilogue: val = acc - wsum[k]*cw[k][c] (f32 cw) ----
    float* dst = USE_WS ? (outp + (size_t)blockIdx.x * K_ * C_)
                        : (outp + (size_t)b * K_ * C_);
    #pragma unroll
    for (int t = 0; t < 4; ++t) {
        const int c = wave * 128 + t * 32 + l31;
        #pragma unroll
        for (int rr = 0; rr < 16; ++rr) {
            const int k = (rr & 3) + 8 * (rr >> 2) + 4 * lh;
            const float val = acc[t][rr] - wacc[rr] * cw[k * C_ + c];
            if (USE_WS) dst[k * C_ + c] = val;
            else        atomicAdd(dst + k * C_ + c, val);
        }
    }
}

// out[b][k][c] = sum_{ch<32} part[b*32+ch][k][c];  grid 256 x 256, float4
__global__ __launch_bounds__(256)
void reduce_kernel(const float4* __restrict__ part, float4* __restrict__ out)
{
    const int gid = blockIdx.x * 256 + threadIdx.x;   // 0..65535
    const int bb  = gid >> 12;                        // 4096 float4 per batch
    const int i4  = gid & 4095;
    const float4* pp = part + ((size_t)bb * NCH) * 4096 + i4;
    float4 s = make_float4(0.f, 0.f, 0.f, 0.f);
    #pragma unroll
    for (int j = 0; j < NCH; ++j) {
        const float4 v = pp[(size_t)j * 4096];
        s.x += v.x; s.y += v.y; s.z += v.z; s.w += v.w;
    }
    out[gid] = s;
}

extern "C" void kernel_launch(void* const* d_in, const int* in_sizes, int n_in,
                              void* d_out, int out_size, void* d_ws, size_t ws_size,
                              hipStream_t stream) {
    const float* x     = (const float*)d_in[0];
    const float* cw    = (const float*)d_in[1];
    const float* scale = (const float*)d_in[2];
    float* out = (float*)d_out;

    const size_t ws_need = (size_t)NBLK * K_ * C_ * sizeof(float);  // 32 MiB
    if (ws_size >= ws_need) {
        float* part = (float*)d_ws;
        hipLaunchKernelGGL(enc_kernel<1>, dim3(NBLK), dim3(256), 0, stream,
                           x, cw, scale, part);
        hipLaunchKernelGGL(reduce_kernel, dim3(256), dim3(256), 0, stream,
                           (const float4*)part, (float4*)out);
    } else {
        hipMemsetAsync(out, 0, (size_t)out_size * sizeof(float), stream);
        hipLaunchKernelGGL(enc_kernel<0>, dim3(NBLK), dim3(256), 0, stream,
                           x, cw, scale, out);
    }
}

// Round 6
// 220.629 us; speedup vs baseline: 1.0243x; 1.0243x over previous
//
#include <hip/hip_runtime.h>

// Encoding layer. B=16, C=512, N=4096, K=32.
// v7: never-drained HBM intake. Busy-sum over v0-v6 counters shows ~85% of
// enc cycles are memory-latency stall: every variant issues staging bursts
// then fully drains them (syncthreads vmcnt(0) / consume-next-inst), so the
// average outstanding bytes per CU are a few KB -> 2.7 B/cy/CU demand.
// Fix: stage GEMM1's x via global_load_lds (no VGPR result -> compiler cannot
// serialize it), 2-slab ring (64c x 128n f32, 32 KB each), counted
// s_waitcnt vmcnt(8) so one slab is ALWAYS in flight; barriers are lgkm-only.
// MFMA B-frags read straight from the f32 slab (ds_read_b32 + f2bf), so the
// bf16 XC tile and its repack pass are gone. A-frags (cw) from L2-hot global,
// converted in-register (proven v3+). Softmax lane-local (v5), GEMM2 global
// register ring / epilogue / reduce unchanged (proven v0).

#define B_ 16
#define C_ 512
#define N_ 4096
#define K_ 32
#define CHUNK 128                 // tokens per block
#define NCH (N_ / CHUNK)          // 32 chunks per batch
#define NBLK (B_ * NCH)           // 512 blocks
#define WLS 40                    // Wl n-stride (u16): 80 B

typedef __attribute__((ext_vector_type(8))) short short8;
typedef __attribute__((ext_vector_type(16))) float floatx16;

__device__ inline unsigned short f2bf(float f) {
    union { float f; unsigned u; } v; v.f = f;
    unsigned r = v.u + 0x7FFFu + ((v.u >> 16) & 1u);  // RNE
    return (unsigned short)(r >> 16);
}

// LDS-drain-only barrier: keeps global/LDS-bound loads (vmcnt) in flight.
__device__ inline void cbar() {
    __builtin_amdgcn_sched_barrier(0);
    asm volatile("s_waitcnt lgkmcnt(0)" ::: "memory");
    __builtin_amdgcn_s_barrier();
    __builtin_amdgcn_sched_barrier(0);
}

__device__ inline void wait_vm8() {
    __builtin_amdgcn_sched_barrier(0);
    asm volatile("s_waitcnt vmcnt(8)" ::: "memory");
    __builtin_amdgcn_sched_barrier(0);
}

template <int USE_WS>
__global__ __launch_bounds__(256, 2)
void enc_kernel(const float* __restrict__ x,
                const float* __restrict__ cw,
                const float* __restrict__ scale,
                float* __restrict__ outp)
{
    __shared__ float slabF[2][64 * CHUNK];       // x f32 slab ring, 65536 B
    __shared__ unsigned short Wl[4][K_ * WLS];   // softmax w bf16 [tile][k][n], 10240 B
    __shared__ float csq[K_];
    __shared__ float scl[K_];

    const int tid  = threadIdx.x;
    const int wave = tid >> 6;
    const int lane = tid & 63;
    const int l31  = lane & 31;
    const int lh   = lane >> 5;

    const int b     = blockIdx.x >> 5;           // NCH = 32
    const int chunk = blockIdx.x & (NCH - 1);
    const float* xb = x + (long)b * C_ * N_;

    // slab staging: 8 global_load_lds_dwordx4 per wave per slab; instruction m
    // stages rows {m*8 + wave*2, +1} (lanes 0-31 / 32-63), tokens (l31)*4..+3.
    // LDS dest is wave-uniform base + lane*16 -> linear [64][128] f32 layout.
#define SLAB_ISSUE(p_, g_)                                                     \
    { _Pragma("unroll")                                                        \
      for (int m = 0; m < 8; ++m) {                                            \
          const float* gsrc_ = xb                                              \
              + (long)((g_) * 64 + m * 8 + wave * 2 + lh) * N_                 \
              + chunk * CHUNK + l31 * 4;                                       \
          __builtin_amdgcn_global_load_lds(                                    \
              (const __attribute__((address_space(1))) unsigned int*)gsrc_,    \
              (__attribute__((address_space(3))) unsigned int*)                \
                  &slabF[p_][(m * 8 + wave * 2) * CHUNK],                      \
              16, 0, 0);                                                       \
      } }

    // ---- prologue: start HBM intake first, then csq/scl under its latency ----
    SLAB_ISSUE(0, 0)

    if (tid < K_) scl[tid] = scale[tid];
    {
        const int k = tid >> 3, q = tid & 7;      // k row, 64-c slice
        const float4* src = (const float4*)(cw + k * C_ + q * 64);
        float ssum = 0.f;
        #pragma unroll
        for (int i = 0; i < 16; ++i) {
            const float4 v = src[i];
            ssum += v.x*v.x + v.y*v.y + v.z*v.z + v.w*v.w;
        }
        ssum += __shfl_xor(ssum, 1);
        ssum += __shfl_xor(ssum, 2);
        ssum += __shfl_xor(ssum, 4);
        if (q == 0) csq[k] = ssum;
    }

    // GEMM1 A-fragments: f32 cw rows (L2-hot) converted in-register.
    const float* cwr = cw + l31 * C_ + lh * 8;
    short8 afA[4], afB[4];
#define AFLOADG(buf_, ptr_)                                                    \
    { _Pragma("unroll")                                                        \
      for (int s = 0; s < 4; ++s) {                                            \
          const float4 u0 = *(const float4*)((ptr_) + s * 16);                 \
          const float4 u1 = *(const float4*)((ptr_) + s * 16 + 4);             \
          short8 t_;                                                           \
          t_[0] = (short)f2bf(u0.x); t_[1] = (short)f2bf(u0.y);                \
          t_[2] = (short)f2bf(u0.z); t_[3] = (short)f2bf(u0.w);                \
          t_[4] = (short)f2bf(u1.x); t_[5] = (short)f2bf(u1.y);                \
          t_[6] = (short)f2bf(u1.z); t_[7] = (short)f2bf(u1.w);                \
          buf_[s] = t_; } }

    AFLOADG(afA, cwr)

    floatx16 S;
    #pragma unroll
    for (int i = 0; i < 16; ++i) S[i] = 0.f;
    float xs = 0.f;

    // ========== GEMM1: S[k][n] = cw @ x, slab-ring pipelined ==========
    // Per iter g: b1 (consume of g-1 done block-wide) -> issue slab g+1 ->
    // vmcnt(8) (slab g landed; g+1 stays in flight) -> b2 -> MFMA off slab g.
    #pragma unroll
    for (int g = 0; g < 8; ++g) {
        cbar();                               // b1: slab g-1 reads done (lgkm only)
        if (g + 1 < 8) SLAB_ISSUE((g + 1) & 1, g + 1)
        wait_vm8();                           // own slab-g loads landed
        cbar();                               // b2: everyone's slab-g loads landed
        if (g + 1 < 8) {
            if (g & 1) AFLOADG(afA, cwr + (g + 1) * 64)
            else       AFLOADG(afB, cwr + (g + 1) * 64)
        }
        #pragma unroll
        for (int s = 0; s < 4; ++s) {
            short8 bx;
            #pragma unroll
            for (int j = 0; j < 8; ++j) {
                const float xv = slabF[g & 1][(s * 16 + lh * 8 + j) * CHUNK
                                              + wave * 32 + l31];
                xs += xv * xv;
                bx[j] = (short)f2bf(xv);
            }
            S = __builtin_amdgcn_mfma_f32_32x32x16_bf16(
                    (g & 1) ? afB[s] : afA[s], bx, S, 0, 0, 0);
        }
    }

    // lane pair (lh=0, lh=1) covered complementary c-halves for token l31
    xs += __shfl_xor(xs, 32);

    // ---- GEMM2 ring prefetch (independent of softmax; flies through it) ----
    float4 bv[6][2];
#define G2LOAD(bi_, i_)                                                        \
    { const int t_ = (i_) >> 3, st_ = (i_) & 7;                                \
      const int c_ = wave * 128 + t_ * 32 + l31;                               \
      const int no_ = (st_ >> 1) * 32 + (st_ & 1) * 16 + lh * 8;               \
      const float* p_ = xb + (long)c_ * N_ + chunk * CHUNK + no_;              \
      bv[bi_][0] = *(const float4*)p_;                                         \
      bv[bi_][1] = *(const float4*)(p_ + 4); }
    G2LOAD(0, 0)
    G2LOAD(1, 1)
    G2LOAD(2, 2)
    G2LOAD(3, 3)
    G2LOAD(4, 4)
    G2LOAD(5, 5)

    // ---- softmax over k: lane pair (l31, l31+32) holds 16 k's each ----
    {
        const float xq = xs;
        float L[16], mx = -3.4e38f;
        #pragma unroll
        for (int rr = 0; rr < 16; ++rr) {
            const int k = (rr & 3) + 8 * (rr >> 2) + 4 * lh;
            L[rr] = scl[k] * (xq - 2.f * S[rr] + csq[k]);
            mx = fmaxf(mx, L[rr]);
        }
        mx = fmaxf(mx, __shfl_xor(mx, 32));
        float sum = 0.f;
        #pragma unroll
        for (int rr = 0; rr < 16; ++rr) { L[rr] = __expf(L[rr] - mx); sum += L[rr]; }
        sum += __shfl_xor(sum, 32);
        const float inv = 1.f / sum;
        #pragma unroll
        for (int rr = 0; rr < 16; ++rr) {
            const int k = (rr & 3) + 8 * (rr >> 2) + 4 * lh;
            Wl[wave][k * WLS + l31] = f2bf(L[rr] * inv);
        }
    }
    cbar();      // Wl handoff

    // ========== GEMM2: enc[k][c] = sum_n W[k][n] x[n][c] ==========
    short8 aw[8];
    #pragma unroll
    for (int st = 0; st < 8; ++st)
        aw[st] = *(const short8*)&Wl[st >> 1][l31 * WLS + (st & 1) * 16 + lh * 8];

    floatx16 wacc;
    #pragma unroll
    for (int i = 0; i < 16; ++i) wacc[i] = 0.f;
    {
        short8 ones;
        #pragma unroll
        for (int j = 0; j < 8; ++j) ones[j] = (short)0x3F80;
        #pragma unroll
        for (int st = 0; st < 8; ++st)
            wacc = __builtin_amdgcn_mfma_f32_32x32x16_bf16(aw[st], ones, wacc, 0, 0, 0);
    }

    floatx16 acc[4];
    #pragma unroll
    for (int t = 0; t < 4; ++t)
        #pragma unroll
        for (int i = 0; i < 16; ++i) acc[t][i] = 0.f;

    #pragma unroll
    for (int i = 0; i < 32; ++i) {               // i = t*8 + st
        const int bi = i % 6;
        const int t  = i >> 3, st = i & 7;
        const float4 v0 = bv[bi][0];
        const float4 v1 = bv[bi][1];
        short8 bx;
        bx[0] = (short)f2bf(v0.x); bx[1] = (short)f2bf(v0.y);
        bx[2] = (short)f2bf(v0.z); bx[3] = (short)f2bf(v0.w);
        bx[4] = (short)f2bf(v1.x); bx[5] = (short)f2bf(v1.y);
        bx[6] = (short)f2bf(v1.z); bx[7] = (short)f2bf(v1.w);
        acc[t] = __builtin_amdgcn_mfma_f32_32x32x16_bf16(aw[st], bx, acc[t], 0, 0, 0);
        if (i + 6 < 32) G2LOAD(bi, i + 6)
    }

    // ---- epilogue: val = acc - wsum[k]*cw[k][c] (f32 cw) ----
    float* dst = USE_WS ? (outp + (size_t)blockIdx.x * K_ * C_)
                        : (outp + (size_t)b * K_ * C_);
    #pragma unroll
    for (int t = 0; t < 4; ++t) {
        const int c = wave * 128 + t * 32 + l31;
        #pragma unroll
        for (int rr = 0; rr < 16; ++rr) {
            const int k = (rr & 3) + 8 * (rr >> 2) + 4 * lh;
            const float val = acc[t][rr] - wacc[rr] * cw[k * C_ + c];
            if (USE_WS) dst[k * C_ + c] = val;
            else        atomicAdd(dst + k * C_ + c, val);
        }
    }
}

// out[b][k][c] = sum_{ch<32} part[b*32+ch][k][c];  grid 256 x 256, float4
__global__ __launch_bounds__(256)
void reduce_kernel(const float4* __restrict__ part, float4* __restrict__ out)
{
    const int gid = blockIdx.x * 256 + threadIdx.x;   // 0..65535
    const int bb  = gid >> 12;                        // 4096 float4 per batch
    const int i4  = gid & 4095;
    const float4* pp = part + ((size_t)bb * NCH) * 4096 + i4;
    float4 s = make_float4(0.f, 0.f, 0.f, 0.f);
    #pragma unroll
    for (int j = 0; j < NCH; ++j) {
        const float4 v = pp[(size_t)j * 4096];
        s.x += v.x; s.y += v.y; s.z += v.z; s.w += v.w;
    }
    out[gid] = s;
}

extern "C" void kernel_launch(void* const* d_in, const int* in_sizes, int n_in,
                              void* d_out, int out_size, void* d_ws, size_t ws_size,
                              hipStream_t stream) {
    const float* x     = (const float*)d_in[0];
    const float* cw    = (const float*)d_in[1];
    const float* scale = (const float*)d_in[2];
    float* out = (float*)d_out;

    const size_t ws_need = (size_t)NBLK * K_ * C_ * sizeof(float);  // 32 MiB
    if (ws_size >= ws_need) {
        float* part = (float*)d_ws;
        hipLaunchKernelGGL(enc_kernel<1>, dim3(NBLK), dim3(256), 0, stream,
                           x, cw, scale, part);
        hipLaunchKernelGGL(reduce_kernel, dim3(256), dim3(256), 0, stream,
                           (const float4*)part, (float4*)out);
    } else {
        hipMemsetAsync(out, 0, (size_t)out_size * sizeof(float), stream);
        hipLaunchKernelGGL(enc_kernel<0>, dim3(NBLK), dim3(256), 0, stream,
                           x, cw, scale, out);
    }
}